// Round 4
// baseline (139.076 us; speedup 1.0000x reference)
//
#include <hip/hip_runtime.h>

// Orbitals_ent: sorted-occupancy gather.
// x: (2048, 256) int32 in {-1,+1}
// orbitals_mf: (512, 256) f32, orbitals_hf: (512, 64) f32
// out: (2048, 256, 320) f32 = orbitals_full[idx], idx = ascending indices of
// occupied spin-orbitals (ups first, then downs, each ascending by site).
//
// R1: row-gather from L2, 132 us (5.1 TB/s wr; fill-kernel ceiling 6.7 TB/s).
// R2: nontemporal stores + unroll: neutral (134 us).
// R3: LDS-staged column slices — FAILED: used source col0 as output offset for
//     hf groups (clobbered cols 0-63, left cols 256-319 zero).
// R4: fix out_col0 = NMF + (cg-8)*CW for hf groups. Structure unchanged.

#define NS 256   // sites (= rows gathered per batch)
#define NMF 256  // mf columns
#define NHF 64   // hf columns
#define NROW 320 // NMF + NHF
#define G 10     // column groups of 32 floats (8 mf + 2 hf)
#define CW 32    // slice width in floats
#define NBG 51   // batch groups (grid = G*NBG = 510 blocks ~= 2 per CU)
#define THREADS 512

typedef float v4f __attribute__((ext_vector_type(4)));

__global__ __launch_bounds__(THREADS, 4) void gather_orbitals(
    const int* __restrict__ x,
    const float* __restrict__ mf,
    const float* __restrict__ hf,
    float* __restrict__ out)
{
    extern __shared__ float smem[];            // 512*32 floats orb slice
    float* orb  = smem;                        // [512][32], bank-rotated
    int*   srcs = (int*)(smem + 512 * CW);     // [2][256] dest->src row
    int*   wtot = srcs + 2 * NS;               // [8] per-wave up counts

    const int cg = blockIdx.x % G;
    const int bg = blockIdx.x / G;

    const float* srcp; int pitch, src_col0, out_col0;
    if (cg < 8) { srcp = mf; pitch = NMF; src_col0 = cg * CW;       out_col0 = cg * CW; }
    else        { srcp = hf; pitch = NHF; src_col0 = (cg - 8) * CW; out_col0 = NMF + (cg - 8) * CW; }

    const int tid  = threadIdx.x;
    const int half = tid >> 8;      // 0/1 (half-block = 4 waves = one batch)
    const int t    = tid & 255;     // thread within half (= site index)
    const int wave = tid >> 6;      // 0..7 global wave id
    const int lane = tid & 63;

    // --- stage this block's 512x32 column slice into LDS (bank-rotated) ---
    {
        const int gl = tid & 7;     // 16B chunk within row
        const int jr = tid >> 3;    // 64 rows per iteration
#pragma unroll
        for (int i = 0; i < 8; ++i) {
            const int j = i * 64 + jr;
            const v4f v = *(const v4f*)(srcp + (size_t)j * pitch + src_col0 + gl * 4);
#pragma unroll
            for (int k = 0; k < 4; ++k)
                orb[(j << 5) + ((gl * 4 + k + j) & 31)] = v[k];
        }
    }
    __syncthreads();

    // --- batch range for this batch-group (2048 = 8*41 + 43*40) ---
    const int nb     = 40 + (bg < 8);
    const int bstart = bg * 40 + (bg < 8 ? bg : 8);

    const int li = t & 31;          // lane within output row chunk
    const int r0 = t >> 5;          // 0..7 row offset per pass

    for (int ib = 0; ib < nb; ib += 2) {
        const int  bi    = ib + half;
        const bool valid = bi < nb;
        const int  b0    = bstart + bi;

        // permutation: prefix-sum of up-occupancy over this half's 256 sites
        bool up = false;
        if (valid) up = (x[(size_t)b0 * NS + t] == 1);
        const unsigned long long m = __ballot(valid && up);
        const int lane_ex = __popcll(m & ((1ull << lane) - 1ull));
        if (lane == 0) wtot[wave] = __popcll(m);
        __syncthreads();
        if (valid) {
            const int wbase = half * 4, wl = wave & 3;
            int woff = 0, nup = 0;
#pragma unroll
            for (int w = 0; w < 4; ++w) {
                const int c = wtot[wbase + w];
                if (w < wl) woff += c;
                nup += c;
            }
            const int upex = woff + lane_ex;
            const int dest = up ? upex : (nup + (t - upex));
            srcs[half * NS + dest] = up ? t : (NS + t);
        }
        __syncthreads();
        if (valid) {
            float* outb = out + (size_t)b0 * NS * NROW + out_col0;
#pragma unroll 8
            for (int p = 0; p < 32; ++p) {
                const int r = p * 8 + r0;
                const int s = srcs[half * NS + r];
                const float v = orb[(s << 5) + ((li + s) & 31)];
                outb[(size_t)r * NROW + li] = v;
            }
        }
        __syncthreads();   // protect srcs/wtot before next iteration
    }
}

extern "C" void kernel_launch(void* const* d_in, const int* in_sizes, int n_in,
                              void* d_out, int out_size, void* d_ws, size_t ws_size,
                              hipStream_t stream) {
    const int*   x  = (const int*)d_in[0];
    const float* mf = (const float*)d_in[1];
    const float* hf = (const float*)d_in[2];
    float* out = (float*)d_out;

    const int lds_bytes = 512 * CW * 4 + 2 * NS * 4 + 8 * 4;   // 67,616 B
    (void)hipFuncSetAttribute((const void*)gather_orbitals,
                              hipFuncAttributeMaxDynamicSharedMemorySize,
                              lds_bytes);
    gather_orbitals<<<dim3(G * NBG), dim3(THREADS), lds_bytes, stream>>>(x, mf, hf, out);
}

// Round 5
// 127.851 us; speedup vs baseline: 1.0878x; 1.0878x over previous
//
#include <hip/hip_runtime.h>

// Orbitals_ent: sorted-occupancy gather.
// x: (2048, 256) int32 in {-1,+1}
// orbitals_mf: (512, 256) f32, orbitals_hf: (512, 64) f32
// out: (2048, 256, 320) f32 = orbitals_full[idx], idx = ascending indices of
// occupied spin-orbitals (ups first, then downs, each ascending by site).
//
// R1: row-gather from L2, 132 us (5.1 TB/s write; fill-kernel ceiling 6.7).
// R2: nontemporal stores + unroll: neutral (134 us).
// R3: LDS column slices — FAILED (hf output offset bug).
// R4: R3 fixed: 139 us. Pure-write HBM didn't help -> read interference dead.
// R5: attack store ORDER + load CONCURRENCY: per wave, 8 contiguous rows per
//     superstep; batch all 10 loads (8 mf + 2 wave-wide hf) into regs, then
//     store rows fully in address order (no separated hf pass, no page
//     revisit; 10 loads in flight per wave).

#define NBATCH 2048
#define NS 256   // sites (= rows gathered per batch)
#define NMF 256  // mf columns
#define NHF 64   // hf columns
#define NROW 320 // NMF + NHF

typedef float v4f __attribute__((ext_vector_type(4)));

__global__ __launch_bounds__(256) void gather_orbitals(
    const int* __restrict__ x,
    const float* __restrict__ mf,
    const float* __restrict__ hf,
    float* __restrict__ out)
{
    __shared__ int src[NS];   // dest row -> source spin-orbital row
    __shared__ int wtot[4];   // per-wave up counts

    const int b    = blockIdx.x;
    const int tid  = threadIdx.x;
    const int wave = tid >> 6;
    const int lane = tid & 63;

    // --- build dest->src permutation via prefix-sum of up-occupancy ---
    const int xv = x[(size_t)b * NS + tid];
    const bool up = (xv == 1);
    const unsigned long long m = __ballot(up);             // 64-bit on CDNA
    const int lane_ex = __popcll(m & ((1ull << lane) - 1ull));
    if (lane == 0) wtot[wave] = __popcll(m);
    __syncthreads();

    int woff = 0, nup = 0;
#pragma unroll
    for (int w = 0; w < 4; ++w) {
        const int c = wtot[w];
        if (w < wave) woff += c;
        nup += c;
    }
    const int upex = woff + lane_ex;          // #ups among sites < tid
    const int dest = up ? upex : (nup + (tid - upex));
    src[dest] = up ? tid : (NS + tid);
    __syncthreads();

    float* outb = out + (size_t)b * NS * NROW;
    const int j16 = lane >> 4;   // which of 4 rows this lane's hf chunk feeds
    const int l16 = lane & 15;   // float4 index within a 64-float hf tail

    // --- 8 supersteps x 4 waves x 8 contiguous rows ---
    for (int ss = 0; ss < 8; ++ss) {
        const int rbase = ss * 32 + wave * 8;

        int s[8];
#pragma unroll
        for (int k = 0; k < 8; ++k) s[k] = src[rbase + k];

        v4f vm[8];
#pragma unroll
        for (int k = 0; k < 8; ++k)
            vm[k] = ((const v4f*)(mf + (size_t)s[k] * NMF))[lane];

        const int sh0 = src[rbase + j16];
        const int sh1 = src[rbase + 4 + j16];
        const v4f vh0 = ((const v4f*)(hf + (size_t)sh0 * NHF))[l16];
        const v4f vh1 = ((const v4f*)(hf + (size_t)sh1 * NHF))[l16];

        // stores in strict address order: rows rbase..rbase+3 fully, then +4..+7
#pragma unroll
        for (int k = 0; k < 4; ++k)
            ((v4f*)(outb + (size_t)(rbase + k) * NROW))[lane] = vm[k];
        ((v4f*)(outb + (size_t)(rbase + j16) * NROW + NMF))[l16] = vh0;
#pragma unroll
        for (int k = 4; k < 8; ++k)
            ((v4f*)(outb + (size_t)(rbase + k) * NROW))[lane] = vm[k];
        ((v4f*)(outb + (size_t)(rbase + 4 + j16) * NROW + NMF))[l16] = vh1;
    }
}

extern "C" void kernel_launch(void* const* d_in, const int* in_sizes, int n_in,
                              void* d_out, int out_size, void* d_ws, size_t ws_size,
                              hipStream_t stream) {
    const int*   x  = (const int*)d_in[0];
    const float* mf = (const float*)d_in[1];
    const float* hf = (const float*)d_in[2];
    float* out = (float*)d_out;

    gather_orbitals<<<dim3(NBATCH), dim3(256), 0, stream>>>(x, mf, hf, out);
}